// Round 2
// baseline (350.820 us; speedup 1.0000x reference)
//
#include <hip/hip_runtime.h>

// Conv2d NCHW, stride=1, pad=1, N=16, C=8, K=8, H=W=1024, 3x3, fp32.
// w-vectorized: each thread computes 4 consecutive w outputs x R rows x 8 co.
// Per input row per ci: one float4 load + 2 edge scalars (vs 12 scalar loads
// for the same 4 outputs in round 1). Weights wave-uniform -> SGPR operands.

#define R 2
#define HH 1024
#define WW 1024
#define CI 8
#define CO 8

__global__ __launch_bounds__(256) void conv3x3_kernel(
    const float* __restrict__ x,      // [16][8][1024][1024]
    const float* __restrict__ wgt,    // [8][8][3][3]
    const float* __restrict__ bias,   // [8]
    float* __restrict__ out)          // [16][8][1024][1024]
{
    const int w0 = threadIdx.x * 4;            // 0..1020, 16B aligned
    const int h0 = blockIdx.x * R;             // 0..1022
    const int n  = blockIdx.y;                 // 0..15

    const long HW = (long)HH * WW;
    const float* xn = x + (long)n * CI * HW;

    float acc[CO][R][4];
#pragma unroll
    for (int co = 0; co < CO; ++co) {
        const float b = bias[co];              // uniform -> s_load
#pragma unroll
        for (int r = 0; r < R; ++r)
#pragma unroll
            for (int p = 0; p < 4; ++p) acc[co][r][p] = b;
    }

    for (int ci = 0; ci < CI; ++ci) {          // uniform loop, not unrolled
        const float* xc = xn + (long)ci * HW;

        // Stage R+2 input rows, 6 floats each: [w0-1 .. w0+4], zero-padded.
        float in[R + 2][6];
#pragma unroll
        for (int r = 0; r < R + 2; ++r) {
            const int h = h0 - 1 + r;
            const bool hv = (h >= 0) && (h < HH);   // block-uniform
            const float* row = xc + (long)h * WW;
            float4 mid;
            float left, right;
            if (hv) {
                mid   = *reinterpret_cast<const float4*>(row + w0);
                left  = (w0 > 0)        ? row[w0 - 1] : 0.0f;   // lane 0 only pads
                right = (w0 + 4 < WW)   ? row[w0 + 4] : 0.0f;   // last lane only pads
            } else {
                mid = make_float4(0.f, 0.f, 0.f, 0.f);
                left = 0.f; right = 0.f;
            }
            in[r][0] = left;
            in[r][1] = mid.x; in[r][2] = mid.y; in[r][3] = mid.z; in[r][4] = mid.w;
            in[r][5] = right;
        }

        // 8 co x R rows x 4 w x 9 taps.
#pragma unroll
        for (int co = 0; co < CO; ++co) {
            const float* wp = wgt + ((co * CI + ci) * 9);
            float wv[9];
#pragma unroll
            for (int k = 0; k < 9; ++k) wv[k] = wp[k];   // uniform -> SGPR
#pragma unroll
            for (int r = 0; r < R; ++r)
#pragma unroll
                for (int kh = 0; kh < 3; ++kh)
#pragma unroll
                    for (int kw = 0; kw < 3; ++kw)
#pragma unroll
                        for (int p = 0; p < 4; ++p)
                            acc[co][r][p] = fmaf(in[r + kh][p + kw], wv[kh * 3 + kw],
                                                 acc[co][r][p]);
        }
    }

    // Stores: one float4 per (co, r) — consecutive lanes contiguous.
#pragma unroll
    for (int co = 0; co < CO; ++co) {
        float* op = out + ((long)n * CO + co) * HW + (long)h0 * WW + w0;
#pragma unroll
        for (int r = 0; r < R; ++r) {
            float4 v = make_float4(acc[co][r][0], acc[co][r][1],
                                   acc[co][r][2], acc[co][r][3]);
            *reinterpret_cast<float4*>(op + (long)r * WW) = v;
        }
    }
}

extern "C" void kernel_launch(void* const* d_in, const int* in_sizes, int n_in,
                              void* d_out, int out_size, void* d_ws, size_t ws_size,
                              hipStream_t stream) {
    const float* x    = (const float*)d_in[0];
    const float* wgt  = (const float*)d_in[1];
    const float* bias = (const float*)d_in[2];
    float* out = (float*)d_out;

    dim3 grid(HH / R, 16, 1);   // (512, 16)
    dim3 block(256, 1, 1);
    conv3x3_kernel<<<grid, block, 0, stream>>>(x, wgt, bias, out);
}